// Round 8
// baseline (586.751 us; speedup 1.0000x reference)
//
#include <hip/hip_runtime.h>

typedef _Float16 half_t;
typedef half_t half8 __attribute__((ext_vector_type(8)));
typedef half_t half4 __attribute__((ext_vector_type(4)));
typedef float f32x4 __attribute__((ext_vector_type(4)));
typedef __attribute__((address_space(1))) const void gc_t;
typedef __attribute__((address_space(3))) void ls_t;

#define NAGENT 32768
#define MAXN   16
#define HD     128
#define QCOLS  65
#define QN     (NAGENT * QCOLS)
#define AGB    16                // agents per block
#define EPB    (AGB * MAXN)     // 256 edges per block

// ws layout (half_t element offsets) — f16 transposed weights WT[n][k]
#define O_WMT   0                // [128][64]  W_msg  (k: fn 0..31, ef 32..39, 0-pad)
#define O_WE1E  8192             // [128][64]  W_e1 edge part (fn rows 0..31, ef rows 160..167)
#define O_WE1H  16384            // [128][128] W_e1 h part (rows 32..159)
#define O_WUPD  32768            // [128][160] W_upd
#define O_WX    53248            // [384][128] W_x
#define O_WH    102400           // [384][128] W_h
#define W_TOTAL 151552

#define MFMA(a, b, c) __builtin_amdgcn_mfma_f32_16x16x32_f16((a), (b), (c), 0, 0, 0)
#define NT_AUX 2   // CPol NT (evict-first) for global_load_lds on gfx950

// dst-major weight prep: consecutive threads write consecutive ws elements
__global__ void prep_weights(const float* __restrict__ W_msg, const float* __restrict__ W_upd,
                             const float* __restrict__ W_x, const float* __restrict__ W_h,
                             const float* __restrict__ W_e1, half_t* __restrict__ ws) {
    int i = blockIdx.x * 256 + threadIdx.x;
    if (i >= W_TOTAL) return;
    float v;
    if (i < 8192) {                          // wmT[n][k], Kp=64
        int n = i >> 6, k = i & 63;
        v = (k < 40) ? W_msg[k * HD + n] : 0.f;
    } else if (i < 16384) {                  // we1eT[n][k]: [fn rows, ef rows 160..167]
        int j = i - 8192; int n = j >> 6, k = j & 63;
        v = (k < 32) ? W_e1[k * HD + n] : (k < 40 ? W_e1[(160 + k - 32) * HD + n] : 0.f);
    } else if (i < 32768) {                  // we1hT[n][k] = W_e1 rows 32..159
        int j = i - 16384; int n = j >> 7, k = j & 127;
        v = W_e1[(32 + k) * HD + n];
    } else if (i < 53248) {                  // wupdT[n][k], K=160
        int j = i - 32768; int n = j / 160, k = j - n * 160;
        v = W_upd[k * HD + n];
    } else if (i < 102400) {                 // wxT[n][k], n in [0,384)
        int j = i - 53248; int n = j >> 7, k = j & 127;
        v = W_x[k * 384 + n];
    } else {
        int j = i - 102400; int n = j >> 7, k = j & 127;
        v = W_h[k * 384 + n];
    }
    ws[i] = (half_t)v;
}

__device__ __forceinline__ half8 ldB(const half_t* __restrict__ WT, int kstride, int n0, int k0, int l) {
    return *(const half8*)(WT + (size_t)(n0 + (l & 15)) * kstride + k0 + ((l >> 4) * 8));
}
__device__ __forceinline__ half4 cvt4(f32x4 v) {
    return (half4){(half_t)v[0], (half_t)v[1], (half_t)v[2], (half_t)v[3]};
}
__device__ __forceinline__ half8 cvt8(f32x4 a, f32x4 b) {
    return (half8){(half_t)a[0], (half_t)a[1], (half_t)a[2], (half_t)a[3],
                   (half_t)b[0], (half_t)b[1], (half_t)b[2], (half_t)b[3]};
}
__device__ __forceinline__ f32x4 ldnt4(const float* p) {
    return __builtin_nontemporal_load((const f32x4*)p);
}
__device__ __forceinline__ float sigm(float x) { return 1.f / (1.f + __expf(-x)); }
__device__ __forceinline__ float tanh_fast(float x) { return 1.f - 2.f / (__expf(2.f * x) + 1.f); }

// ============================ fused kernel =================================
// LDS-lean (≈25.9 KB) + NT policy: all single-use streams (gather DMA, ef,
// fa, h_in, h_new store) are non-temporal so the ws weight set stays
// L2-resident; weights keep default caching. 6 blocks/CU target.
__global__ __launch_bounds__(256, 6) void k_fused(
    const float* __restrict__ feat_nbr, const float* __restrict__ feat_agent,
    const float* __restrict__ edge_feat, const float* __restrict__ h_in,
    const float* __restrict__ b_msg, const float* __restrict__ b_upd,
    const float* __restrict__ b_ih, const float* __restrict__ b_hh,
    const float* __restrict__ b_e1, const float* __restrict__ W_e2,
    const float* __restrict__ b_e2, const float* __restrict__ W_a,
    const float* __restrict__ b_a, const int* __restrict__ src_idx,
    const half_t* __restrict__ ws, float* __restrict__ out)
{
    const int t = threadIdx.x;
    const int w = t >> 6, l = t & 63;
    const int l16 = l & 15, q = l >> 4;
    const int a0 = blockIdx.x * AGB;
    const int be = blockIdx.x * EPB;
    const half8 hz = {0, 0, 0, 0, 0, 0, 0, 0};

    __shared__ __align__(16) char raw[16384]; // fng f32 [4 waves][4 slots][64][16B]
                                              //  -> (after b1) h_lds + bufB
    __shared__ half_t efh[EPB][8];            // 4 KB   f16 edge feats (wave-private rows)
    __shared__ half_t bufA[AGB][168];         // 5.25 KB  [agg(0..127)|fa(128..159)] -> hn
    __shared__ float  hnwa[AGB];

    float* fngw = (float*)raw + (w << 10);    // this wave's 4 KB (4 slots x 1 KB)

    if (t < AGB) hnwa[t] = 0.f;

    // ---- 1. indices, then stage-1 gather DMAs (mt=0,1 -> slots 0..3, NT) ----
    int idx[4];
    #pragma unroll
    for (int mt = 0; mt < 4; ++mt)
        idx[mt] = src_idx[be + w * 64 + mt * 16 + l16];
    #pragma unroll
    for (int mt = 0; mt < 2; ++mt) {
        const float* fr = feat_nbr + (size_t)idx[mt] * 32 + q * 8;
        __builtin_amdgcn_global_load_lds((gc_t*)fr,       (ls_t*)(fngw + (mt * 2) * 256),     16, 0, NT_AUX);
        __builtin_amdgcn_global_load_lds((gc_t*)(fr + 4), (ls_t*)(fngw + (mt * 2 + 1) * 256), 16, 0, NT_AUX);
    }

    // ---- 2. coalesced single-use streams (NT), overlap the gather ----
    const float* er = edge_feat + (size_t)(be + t) * 8;
    f32x4 ev0 = ldnt4(er);
    f32x4 ev1 = ldnt4(er + 4);
    f32x4 fa_v = {0.f, 0.f, 0.f, 0.f};
    if (t < 128) fa_v = ldnt4(feat_agent + (size_t)(a0 + (t >> 3)) * 32 + (t & 7) * 4);
    f32x4 h_v0 = ldnt4(h_in + (size_t)(a0 + (t >> 5)) * HD + (t & 31) * 4);
    f32x4 h_v1 = ldnt4(h_in + (size_t)(a0 + 8 + (t >> 5)) * HD + (t & 31) * 4);

    // ---- 3. B-fragments + biases for Phase A (L2-resident weights) ----
    const half_t* wmT = ws + O_WMT;
    half8 Bm[4][4];
    float bm0[4], bm1[4];
    #pragma unroll
    for (int nc = 0; nc < 4; ++nc) {
        const int n0 = nc * 32;
        Bm[nc][0] = ldB(wmT, 64, n0, 0, l);
        Bm[nc][1] = ldB(wmT, 64, n0, 32, l);
        Bm[nc][2] = ldB(wmT, 64, n0 + 16, 0, l);
        Bm[nc][3] = ldB(wmT, 64, n0 + 16, 32, l);
        bm0[nc] = b_msg[n0 + l16];
        bm1[nc] = b_msg[n0 + 16 + l16];
    }

    // ---- 4. drain stage-1 + streams ----
    asm volatile("s_waitcnt vmcnt(0)" ::: "memory");
    __builtin_amdgcn_sched_barrier(0);
    *(half8*)&efh[t][0] = cvt8(ev0, ev1);                 // ef f16, wave-private row t
    if (t < 128) *(half4*)&bufA[t >> 3][128 + (t & 7) * 4] = cvt4(fa_v);

    // read stage-1 slots -> regs (kept live through Phase C)
    half8 af0k[4];
    {
        f32x4 a0v = *(const f32x4*)(fngw + 0 * 256 + l * 4);
        f32x4 a1v = *(const f32x4*)(fngw + 1 * 256 + l * 4);
        f32x4 b0v = *(const f32x4*)(fngw + 2 * 256 + l * 4);
        f32x4 b1v = *(const f32x4*)(fngw + 3 * 256 + l * 4);
        af0k[0] = cvt8(a0v, a1v);
        af0k[1] = cvt8(b0v, b1v);
    }
    // slot reads must complete before stage-2 DMA overwrites them
    asm volatile("s_waitcnt lgkmcnt(0)" ::: "memory");
    __builtin_amdgcn_sched_barrier(0);
    #pragma unroll
    for (int mt = 2; mt < 4; ++mt) {
        const float* fr = feat_nbr + (size_t)idx[mt] * 32 + q * 8;
        __builtin_amdgcn_global_load_lds((gc_t*)fr,       (ls_t*)(fngw + ((mt - 2) * 2) * 256),     16, 0, NT_AUX);
        __builtin_amdgcn_global_load_lds((gc_t*)(fr + 4), (ls_t*)(fngw + ((mt - 2) * 2 + 1) * 256), 16, 0, NT_AUX);
    }

    // ---- Phase A: msg GEMM + segment-sum ----
    auto phA = [&](int mt, half8 af0) {
        const int al = w * 4 + mt;
        const int arow = al * 16 + l16;
        half8 af1 = (q == 0) ? *(const half8*)&efh[arow][0] : hz;
        #pragma unroll
        for (int nc = 0; nc < 4; ++nc) {
            f32x4 c0 = {0.f, 0.f, 0.f, 0.f}, c1 = {0.f, 0.f, 0.f, 0.f};
            c0 = MFMA(af0, Bm[nc][0], c0);
            c0 = MFMA(af1, Bm[nc][1], c0);
            c1 = MFMA(af0, Bm[nc][2], c1);
            c1 = MFMA(af1, Bm[nc][3], c1);
            float s0 = 0.f, s1 = 0.f;
            #pragma unroll
            for (int r = 0; r < 4; ++r) {
                s0 += fmaxf(c0[r] + bm0[nc], 0.f);
                s1 += fmaxf(c1[r] + bm1[nc], 0.f);
            }
            s0 += __shfl_xor(s0, 16); s0 += __shfl_xor(s0, 32);
            s1 += __shfl_xor(s1, 16); s1 += __shfl_xor(s1, 32);
            if (l < 16) {
                bufA[al][nc * 32 + l]      = (half_t)s0;   // agg (f16)
                bufA[al][nc * 32 + 16 + l] = (half_t)s1;
            }
        }
    };
    phA(0, af0k[0]);
    phA(1, af0k[1]);         // stage-2 DMA latency hides under these MFMAs

    asm volatile("s_waitcnt vmcnt(0)" ::: "memory");
    __builtin_amdgcn_sched_barrier(0);
    {
        f32x4 a0v = *(const f32x4*)(fngw + 0 * 256 + l * 4);
        f32x4 a1v = *(const f32x4*)(fngw + 1 * 256 + l * 4);
        f32x4 b0v = *(const f32x4*)(fngw + 2 * 256 + l * 4);
        f32x4 b1v = *(const f32x4*)(fngw + 3 * 256 + l * 4);
        af0k[2] = cvt8(a0v, a1v);
        af0k[3] = cvt8(b0v, b1v);
    }
    phA(2, af0k[2]);
    phA(3, af0k[3]);

    __syncthreads();   // b1: all fng reads done -> region dead; bufA complete

    // carved buffers inside the dead fng region
    half_t* hl = (half_t*)raw;           // h_lds  [16][136]  (4352 B)
    half_t* xb = (half_t*)raw + 2176;    // bufB   [16][136]  (x -> che)
    *(half4*)&hl[(t >> 5) * 136 + (t & 31) * 4] = cvt4(h_v0);
    *(half4*)&hl[(8 + (t >> 5)) * 136 + (t & 31) * 4] = cvt4(h_v1);

    // ---- S2: x = relu([agg|fa]@Wupd + b) -> xb ----
    {
        const half_t* wupdT = ws + O_WUPD;
        half8 af[5];
        #pragma unroll
        for (int k = 0; k < 5; ++k) af[k] = *(const half8*)&bufA[l16][k * 32 + q * 8];
        #pragma unroll
        for (int s = 0; s < 2; ++s) {
            const int n0 = (w * 2 + s) * 16;
            f32x4 c = {0.f, 0.f, 0.f, 0.f};
            #pragma unroll
            for (int k = 0; k < 5; ++k) c = MFMA(af[k], ldB(wupdT, 160, n0, k * 32, l), c);
            float bu = b_upd[n0 + l16];
            #pragma unroll
            for (int r = 0; r < 4; ++r)
                xb[(q * 4 + r) * 136 + n0 + l16] = (half_t)fmaxf(c[r] + bu, 0.f);
        }
    }
    __syncthreads();   // b2: x + h_lds ready

    // ---- S3: GRU; hn -> bufA; fold h_new . W_a[128:256] into hnwa ----
    {
        const half_t* wxT = ws + O_WX;
        const half_t* whT = ws + O_WH;
        half8 ax[4], ah[4];
        #pragma unroll
        for (int k = 0; k < 4; ++k) {
            ax[k] = *(const half8*)&xb[l16 * 136 + k * 32 + q * 8];
            ah[k] = *(const half8*)&hl[l16 * 136 + k * 32 + q * 8];
        }
        float pa[4] = {0.f, 0.f, 0.f, 0.f};
        #pragma unroll
        for (int s = 0; s < 2; ++s) {
            const int colb = w * 32 + s * 16;
            f32x4 gi[3], gh[3];
            #pragma unroll
            for (int g = 0; g < 3; ++g) {
                const int n0 = g * 128 + colb;
                f32x4 ci = {0.f, 0.f, 0.f, 0.f}, ch = {0.f, 0.f, 0.f, 0.f};
                #pragma unroll
                for (int k = 0; k < 4; ++k) {
                    ci = MFMA(ax[k], ldB(wxT, 128, n0, k * 32, l), ci);
                    ch = MFMA(ah[k], ldB(whT, 128, n0, k * 32, l), ch);
                }
                gi[g] = ci; gh[g] = ch;
            }
            const int col = colb + l16;
            float bi0 = b_ih[col], bi1 = b_ih[HD + col], bi2 = b_ih[2 * HD + col];
            float bh0 = b_hh[col], bh1 = b_hh[HD + col], bh2 = b_hh[2 * HD + col];
            float wac = W_a[HD + col];
            #pragma unroll
            for (int r = 0; r < 4; ++r) {
                const int row = q * 4 + r;
                float rg = sigm(gi[0][r] + bi0 + gh[0][r] + bh0);
                float zg = sigm(gi[1][r] + bi1 + gh[1][r] + bh1);
                float ng = tanh_fast(gi[2][r] + bi2 + rg * (gh[2][r] + bh2));
                float hv = (1.f - zg) * ng + zg * (float)hl[row * 136 + col];
                __builtin_nontemporal_store(hv, &out[QN + (size_t)(a0 + row) * HD + col]); // h_new
                bufA[row][col] = (half_t)hv;                    // hn (over agg)
                pa[r] = fmaf(hv, wac, pa[r]);
            }
        }
        #pragma unroll
        for (int r = 0; r < 4; ++r) {
            #pragma unroll
            for (int m = 1; m <= 8; m <<= 1) pa[r] += __shfl_xor(pa[r], m);
            if (l16 == 0) atomicAdd(&hnwa[q * 4 + r], pa[r]);
        }
    }
    __syncthreads();   // b3: hn + hnwa complete

    // ---- S4h: che = h_new @ We1h + b_e1 -> xb (over x) ----
    {
        const half_t* we1hT = ws + O_WE1H;
        half8 an[4];
        #pragma unroll
        for (int k = 0; k < 4; ++k) an[k] = *(const half8*)&bufA[l16][k * 32 + q * 8];
        #pragma unroll
        for (int s = 0; s < 2; ++s) {
            const int n0 = (w * 2 + s) * 16;
            f32x4 c = {0.f, 0.f, 0.f, 0.f};
            #pragma unroll
            for (int k = 0; k < 4; ++k) c = MFMA(an[k], ldB(we1hT, 128, n0, k * 32, l), c);
            float bv = b_e1[n0 + l16];
            #pragma unroll
            for (int r = 0; r < 4; ++r)
                xb[(q * 4 + r) * 136 + n0 + l16] = (half_t)(c[r] + bv);
        }
    }
    __syncthreads();   // b4: che complete

    // ---- Phase C: ze = relu([fn|ef]@We1e + che); q-values + agent scalar ----
    {
        const half_t* we1eT = ws + O_WE1E;
        half8 B[4][4];
        float wa0[4], wa1[4];
        #pragma unroll
        for (int nc = 0; nc < 4; ++nc) {
            const int n0 = nc * 32;
            B[nc][0] = ldB(we1eT, 64, n0, 0, l);
            B[nc][1] = ldB(we1eT, 64, n0, 32, l);
            B[nc][2] = ldB(we1eT, 64, n0 + 16, 0, l);
            B[nc][3] = ldB(we1eT, 64, n0 + 16, 32, l);
            wa0[nc] = W_a[n0 + l16];
            wa1[nc] = W_a[n0 + 16 + l16];
        }
        const float ba = b_a[0];

        auto phC = [&](int mt, half8 af0) {
            const int al = w * 4 + mt;
            const int arow = al * 16 + l16;
            half8 af1 = hz;
            if (q == 0) af1 = *(const half8*)&efh[arow][0];
            float qa[4][4];
            #pragma unroll
            for (int r = 0; r < 4; ++r)
                #pragma unroll
                for (int p = 0; p < 4; ++p) qa[r][p] = 0.f;
            float wa_part = 0.f;
            #pragma unroll
            for (int nc = 0; nc < 4; ++nc) {
                const int n0 = nc * 32;
                f32x4 c0 = {0.f, 0.f, 0.f, 0.f}, c1 = {0.f, 0.f, 0.f, 0.f};
                c0 = MFMA(af0, B[nc][0], c0);
                c0 = MFMA(af1, B[nc][1], c0);
                c1 = MFMA(af0, B[nc][2], c1);
                c1 = MFMA(af1, B[nc][3], c1);
                const int col0 = n0 + l16, col1 = n0 + 16 + l16;
                float ch0 = (float)xb[al * 136 + col0], ch1 = (float)xb[al * 136 + col1];
                f32x4 w20 = *(const f32x4*)(W_e2 + col0 * 4);
                f32x4 w21 = *(const f32x4*)(W_e2 + col1 * 4);
                float s0 = 0.f, s1 = 0.f;
                #pragma unroll
                for (int r = 0; r < 4; ++r) {
                    float z0 = fmaxf(c0[r] + ch0, 0.f);
                    float z1 = fmaxf(c1[r] + ch1, 0.f);
                    s0 += z0; s1 += z1;
                    qa[r][0] = fmaf(z0, w20[0], fmaf(z1, w21[0], qa[r][0]));
                    qa[r][1] = fmaf(z0, w20[1], fmaf(z1, w21[1], qa[r][1]));
                    qa[r][2] = fmaf(z0, w20[2], fmaf(z1, w21[2], qa[r][2]));
                    qa[r][3] = fmaf(z0, w20[3], fmaf(z1, w21[3], qa[r][3]));
                }
                s0 += __shfl_xor(s0, 16); s0 += __shfl_xor(s0, 32);
                s1 += __shfl_xor(s1, 16); s1 += __shfl_xor(s1, 32);
                wa_part = fmaf(s0, wa0[nc], fmaf(s1, wa1[nc], wa_part));
            }
            #pragma unroll
            for (int m = 1; m <= 8; m <<= 1)
                #pragma unroll
                for (int r = 0; r < 4; ++r)
                    #pragma unroll
                    for (int p = 0; p < 4; ++p) qa[r][p] += __shfl_xor(qa[r][p], m);
            if (l16 < 4) {
                const int p = l16;
                const float bz = b_e2[p];
                #pragma unroll
                for (int r = 0; r < 4; ++r)
                    out[(size_t)(a0 + al) * QCOLS + (q * 4 + r) * 4 + p] = qa[r][p] + bz;
            }
            #pragma unroll
            for (int m = 1; m <= 8; m <<= 1) wa_part += __shfl_xor(wa_part, m);
            if (l == 0)
                out[(size_t)(a0 + al) * QCOLS + 64] = wa_part + hnwa[al] + ba;
        };
        phC(0, af0k[0]);
        phC(1, af0k[1]);
        phC(2, af0k[2]);
        phC(3, af0k[3]);
    }
}

extern "C" void kernel_launch(void* const* d_in, const int* in_sizes, int n_in,
                              void* d_out, int out_size, void* d_ws, size_t ws_size,
                              hipStream_t stream) {
    const float* feat_nbr   = (const float*)d_in[0];
    const float* feat_agent = (const float*)d_in[1];
    const float* edge_feat  = (const float*)d_in[2];
    const float* h_in       = (const float*)d_in[3];
    const float* W_msg = (const float*)d_in[4];
    const float* b_msg = (const float*)d_in[5];
    const float* W_upd = (const float*)d_in[6];
    const float* b_upd = (const float*)d_in[7];
    const float* W_x   = (const float*)d_in[8];
    const float* W_h   = (const float*)d_in[9];
    const float* b_ih  = (const float*)d_in[10];
    const float* b_hh  = (const float*)d_in[11];
    const float* W_e1  = (const float*)d_in[12];
    const float* b_e1  = (const float*)d_in[13];
    const float* W_e2  = (const float*)d_in[14];
    const float* b_e2  = (const float*)d_in[15];
    const float* W_a   = (const float*)d_in[16];
    const float* b_a   = (const float*)d_in[17];
    const int* src_idx = (const int*)d_in[18];
    // d_in[19] = dst_idx unused: edges grouped by dst, fixed degree 16.
    half_t* ws = (half_t*)d_ws;
    float* out = (float*)d_out;
    const int nblk = NAGENT / AGB;   // 2048

    prep_weights<<<(W_TOTAL + 255) / 256, 256, 0, stream>>>(W_msg, W_upd, W_x, W_h, W_e1, ws);
    k_fused<<<nblk, 256, 0, stream>>>(feat_nbr, feat_agent, edge_feat, h_in,
                                      b_msg, b_upd, b_ih, b_hh, b_e1,
                                      W_e2, b_e2, W_a, b_a, src_idx, ws, out);
}

// Round 9
// 322.555 us; speedup vs baseline: 1.8191x; 1.8191x over previous
//
#include <hip/hip_runtime.h>

typedef _Float16 half_t;
typedef half_t half8 __attribute__((ext_vector_type(8)));
typedef half_t half4 __attribute__((ext_vector_type(4)));
typedef float f32x4 __attribute__((ext_vector_type(4)));
typedef __attribute__((address_space(1))) const void gc_t;
typedef __attribute__((address_space(3))) void ls_t;

#define NAGENT 32768
#define MAXN   16
#define HD     128
#define QCOLS  65
#define QN     (NAGENT * QCOLS)
#define AGB    16                // agents per block
#define EPB    (AGB * MAXN)     // 256 edges per block

// ws layout (half_t element offsets) — f16 transposed weights WT[n][k]
#define O_WMT   0                // [128][64]  W_msg  (k: fn 0..31, ef 32..39, 0-pad)
#define O_WE1E  8192             // [128][64]  W_e1 edge part (fn rows 0..31, ef rows 160..167)
#define O_WE1H  16384            // [128][128] W_e1 h part (rows 32..159)
#define O_WUPD  32768            // [128][160] W_upd
#define O_WX    53248            // [384][128] W_x
#define O_WH    102400           // [384][128] W_h
#define W_TOTAL 151552

#define MFMA(a, b, c) __builtin_amdgcn_mfma_f32_16x16x32_f16((a), (b), (c), 0, 0, 0)

// dst-major weight prep: consecutive threads write consecutive ws elements
__global__ void prep_weights(const float* __restrict__ W_msg, const float* __restrict__ W_upd,
                             const float* __restrict__ W_x, const float* __restrict__ W_h,
                             const float* __restrict__ W_e1, half_t* __restrict__ ws) {
    int i = blockIdx.x * 256 + threadIdx.x;
    if (i >= W_TOTAL) return;
    float v;
    if (i < 8192) {                          // wmT[n][k], Kp=64
        int n = i >> 6, k = i & 63;
        v = (k < 40) ? W_msg[k * HD + n] : 0.f;
    } else if (i < 16384) {                  // we1eT[n][k]: [fn rows, ef rows 160..167]
        int j = i - 8192; int n = j >> 6, k = j & 63;
        v = (k < 32) ? W_e1[k * HD + n] : (k < 40 ? W_e1[(160 + k - 32) * HD + n] : 0.f);
    } else if (i < 32768) {                  // we1hT[n][k] = W_e1 rows 32..159
        int j = i - 16384; int n = j >> 7, k = j & 127;
        v = W_e1[(32 + k) * HD + n];
    } else if (i < 53248) {                  // wupdT[n][k], K=160
        int j = i - 32768; int n = j / 160, k = j - n * 160;
        v = W_upd[k * HD + n];
    } else if (i < 102400) {                 // wxT[n][k], n in [0,384)
        int j = i - 53248; int n = j >> 7, k = j & 127;
        v = W_x[k * 384 + n];
    } else {
        int j = i - 102400; int n = j >> 7, k = j & 127;
        v = W_h[k * 384 + n];
    }
    ws[i] = (half_t)v;
}

__device__ __forceinline__ half8 ldB(const half_t* __restrict__ WT, int kstride, int n0, int k0, int l) {
    return *(const half8*)(WT + (size_t)(n0 + (l & 15)) * kstride + k0 + ((l >> 4) * 8));
}
__device__ __forceinline__ half4 cvt4(f32x4 v) {
    return (half4){(half_t)v[0], (half_t)v[1], (half_t)v[2], (half_t)v[3]};
}
__device__ __forceinline__ half8 cvt8(f32x4 a, f32x4 b) {
    return (half8){(half_t)a[0], (half_t)a[1], (half_t)a[2], (half_t)a[3],
                   (half_t)b[0], (half_t)b[1], (half_t)b[2], (half_t)b[3]};
}
__device__ __forceinline__ float sigm(float x) { return 1.f / (1.f + __expf(-x)); }
__device__ __forceinline__ float tanh_fast(float x) { return 1.f - 2.f / (__expf(2.f * x) + 1.f); }

// ============================ fused kernel =================================
// LDS-lean (≈25.9 KB: LDS allows 6 blocks/CU); launch_bounds kept at (256,3)
// so the register allocator has the same headroom as the clean 84-VGPR R4
// build — occupancy rises via LDS only, no forced spills (R6/R8 lesson:
// higher min-occupancy bounds made the allocator spill to scratch, which
// showed up as FETCH/WRITE explosions + slowdown).
__global__ __launch_bounds__(256, 3) void k_fused(
    const float* __restrict__ feat_nbr, const float* __restrict__ feat_agent,
    const float* __restrict__ edge_feat, const float* __restrict__ h_in,
    const float* __restrict__ b_msg, const float* __restrict__ b_upd,
    const float* __restrict__ b_ih, const float* __restrict__ b_hh,
    const float* __restrict__ b_e1, const float* __restrict__ W_e2,
    const float* __restrict__ b_e2, const float* __restrict__ W_a,
    const float* __restrict__ b_a, const int* __restrict__ src_idx,
    const half_t* __restrict__ ws, float* __restrict__ out)
{
    const int t = threadIdx.x;
    const int w = t >> 6, l = t & 63;
    const int l16 = l & 15, q = l >> 4;
    const int a0 = blockIdx.x * AGB;
    const int be = blockIdx.x * EPB;
    const half8 hz = {0, 0, 0, 0, 0, 0, 0, 0};

    __shared__ __align__(16) char raw[16384]; // fng f32 [4 waves][4 slots][64][16B]
                                              //  -> (after b1) h_lds + bufB
    __shared__ half_t efh[EPB][8];            // 4 KB   f16 edge feats (wave-private rows)
    __shared__ half_t bufA[AGB][168];         // 5.25 KB  [agg(0..127)|fa(128..159)] -> hn
    __shared__ float  hnwa[AGB];

    float* fngw = (float*)raw + (w << 10);    // this wave's 4 KB (4 slots x 1 KB)

    if (t < AGB) hnwa[t] = 0.f;

    // ---- 1. indices, then stage-1 gather DMAs (mt=0,1 -> slots 0..3) ----
    int idx[4];
    #pragma unroll
    for (int mt = 0; mt < 4; ++mt)
        idx[mt] = src_idx[be + w * 64 + mt * 16 + l16];
    #pragma unroll
    for (int mt = 0; mt < 2; ++mt) {
        const float* fr = feat_nbr + (size_t)idx[mt] * 32 + q * 8;
        __builtin_amdgcn_global_load_lds((gc_t*)fr,       (ls_t*)(fngw + (mt * 2) * 256),     16, 0, 0);
        __builtin_amdgcn_global_load_lds((gc_t*)(fr + 4), (ls_t*)(fngw + (mt * 2 + 1) * 256), 16, 0, 0);
    }

    // ---- 2. coalesced streaming loads overlap the gather latency ----
    const float* er = edge_feat + (size_t)(be + t) * 8;
    f32x4 ev0 = *(const f32x4*)er;
    f32x4 ev1 = *(const f32x4*)(er + 4);
    f32x4 fa_v = {0.f, 0.f, 0.f, 0.f};
    if (t < 128) fa_v = *(const f32x4*)(feat_agent + (size_t)(a0 + (t >> 3)) * 32 + (t & 7) * 4);
    f32x4 h_v0 = *(const f32x4*)(h_in + (size_t)(a0 + (t >> 5)) * HD + (t & 31) * 4);
    f32x4 h_v1 = *(const f32x4*)(h_in + (size_t)(a0 + 8 + (t >> 5)) * HD + (t & 31) * 4);

    // ---- 3. B-fragments + biases for Phase A (L2-hot, overlap too) ----
    const half_t* wmT = ws + O_WMT;
    half8 Bm[4][4];
    float bm0[4], bm1[4];
    #pragma unroll
    for (int nc = 0; nc < 4; ++nc) {
        const int n0 = nc * 32;
        Bm[nc][0] = ldB(wmT, 64, n0, 0, l);
        Bm[nc][1] = ldB(wmT, 64, n0, 32, l);
        Bm[nc][2] = ldB(wmT, 64, n0 + 16, 0, l);
        Bm[nc][3] = ldB(wmT, 64, n0 + 16, 32, l);
        bm0[nc] = b_msg[n0 + l16];
        bm1[nc] = b_msg[n0 + 16 + l16];
    }

    // ---- 4. drain stage-1 + streams ----
    asm volatile("s_waitcnt vmcnt(0)" ::: "memory");
    __builtin_amdgcn_sched_barrier(0);
    *(half8*)&efh[t][0] = cvt8(ev0, ev1);                 // ef f16, wave-private row t
    if (t < 128) *(half4*)&bufA[t >> 3][128 + (t & 7) * 4] = cvt4(fa_v);

    // read stage-1 slots -> regs (kept live through Phase C)
    half8 af0k[4];
    {
        f32x4 a0v = *(const f32x4*)(fngw + 0 * 256 + l * 4);
        f32x4 a1v = *(const f32x4*)(fngw + 1 * 256 + l * 4);
        f32x4 b0v = *(const f32x4*)(fngw + 2 * 256 + l * 4);
        f32x4 b1v = *(const f32x4*)(fngw + 3 * 256 + l * 4);
        af0k[0] = cvt8(a0v, a1v);
        af0k[1] = cvt8(b0v, b1v);
    }
    // slot reads must complete before stage-2 DMA overwrites them
    asm volatile("s_waitcnt lgkmcnt(0)" ::: "memory");
    __builtin_amdgcn_sched_barrier(0);
    #pragma unroll
    for (int mt = 2; mt < 4; ++mt) {
        const float* fr = feat_nbr + (size_t)idx[mt] * 32 + q * 8;
        __builtin_amdgcn_global_load_lds((gc_t*)fr,       (ls_t*)(fngw + ((mt - 2) * 2) * 256),     16, 0, 0);
        __builtin_amdgcn_global_load_lds((gc_t*)(fr + 4), (ls_t*)(fngw + ((mt - 2) * 2 + 1) * 256), 16, 0, 0);
    }

    // ---- Phase A: msg GEMM + segment-sum ----
    auto phA = [&](int mt, half8 af0) {
        const int al = w * 4 + mt;
        const int arow = al * 16 + l16;
        half8 af1 = (q == 0) ? *(const half8*)&efh[arow][0] : hz;
        #pragma unroll
        for (int nc = 0; nc < 4; ++nc) {
            f32x4 c0 = {0.f, 0.f, 0.f, 0.f}, c1 = {0.f, 0.f, 0.f, 0.f};
            c0 = MFMA(af0, Bm[nc][0], c0);
            c0 = MFMA(af1, Bm[nc][1], c0);
            c1 = MFMA(af0, Bm[nc][2], c1);
            c1 = MFMA(af1, Bm[nc][3], c1);
            float s0 = 0.f, s1 = 0.f;
            #pragma unroll
            for (int r = 0; r < 4; ++r) {
                s0 += fmaxf(c0[r] + bm0[nc], 0.f);
                s1 += fmaxf(c1[r] + bm1[nc], 0.f);
            }
            s0 += __shfl_xor(s0, 16); s0 += __shfl_xor(s0, 32);
            s1 += __shfl_xor(s1, 16); s1 += __shfl_xor(s1, 32);
            if (l < 16) {
                bufA[al][nc * 32 + l]      = (half_t)s0;   // agg (f16)
                bufA[al][nc * 32 + 16 + l] = (half_t)s1;
            }
        }
    };
    phA(0, af0k[0]);
    phA(1, af0k[1]);         // stage-2 DMA latency hides under these MFMAs

    asm volatile("s_waitcnt vmcnt(0)" ::: "memory");
    __builtin_amdgcn_sched_barrier(0);
    {
        f32x4 a0v = *(const f32x4*)(fngw + 0 * 256 + l * 4);
        f32x4 a1v = *(const f32x4*)(fngw + 1 * 256 + l * 4);
        f32x4 b0v = *(const f32x4*)(fngw + 2 * 256 + l * 4);
        f32x4 b1v = *(const f32x4*)(fngw + 3 * 256 + l * 4);
        af0k[2] = cvt8(a0v, a1v);
        af0k[3] = cvt8(b0v, b1v);
    }
    phA(2, af0k[2]);
    phA(3, af0k[3]);

    __syncthreads();   // b1: all fng reads done -> region dead; bufA complete

    // carved buffers inside the dead fng region
    half_t* hl = (half_t*)raw;           // h_lds  [16][136]  (4352 B)
    half_t* xb = (half_t*)raw + 2176;    // bufB   [16][136]  (x -> che)
    *(half4*)&hl[(t >> 5) * 136 + (t & 31) * 4] = cvt4(h_v0);
    *(half4*)&hl[(8 + (t >> 5)) * 136 + (t & 31) * 4] = cvt4(h_v1);

    // ---- S2: x = relu([agg|fa]@Wupd + b) -> xb ----
    {
        const half_t* wupdT = ws + O_WUPD;
        half8 af[5];
        #pragma unroll
        for (int k = 0; k < 5; ++k) af[k] = *(const half8*)&bufA[l16][k * 32 + q * 8];
        #pragma unroll
        for (int s = 0; s < 2; ++s) {
            const int n0 = (w * 2 + s) * 16;
            f32x4 c = {0.f, 0.f, 0.f, 0.f};
            #pragma unroll
            for (int k = 0; k < 5; ++k) c = MFMA(af[k], ldB(wupdT, 160, n0, k * 32, l), c);
            float bu = b_upd[n0 + l16];
            #pragma unroll
            for (int r = 0; r < 4; ++r)
                xb[(q * 4 + r) * 136 + n0 + l16] = (half_t)fmaxf(c[r] + bu, 0.f);
        }
    }
    __syncthreads();   // b2: x + h_lds ready

    // ---- S3: GRU; hn -> bufA; fold h_new . W_a[128:256] into hnwa ----
    {
        const half_t* wxT = ws + O_WX;
        const half_t* whT = ws + O_WH;
        half8 ax[4], ah[4];
        #pragma unroll
        for (int k = 0; k < 4; ++k) {
            ax[k] = *(const half8*)&xb[l16 * 136 + k * 32 + q * 8];
            ah[k] = *(const half8*)&hl[l16 * 136 + k * 32 + q * 8];
        }
        float pa[4] = {0.f, 0.f, 0.f, 0.f};
        #pragma unroll
        for (int s = 0; s < 2; ++s) {
            const int colb = w * 32 + s * 16;
            f32x4 gi[3], gh[3];
            #pragma unroll
            for (int g = 0; g < 3; ++g) {
                const int n0 = g * 128 + colb;
                f32x4 ci = {0.f, 0.f, 0.f, 0.f}, ch = {0.f, 0.f, 0.f, 0.f};
                #pragma unroll
                for (int k = 0; k < 4; ++k) {
                    ci = MFMA(ax[k], ldB(wxT, 128, n0, k * 32, l), ci);
                    ch = MFMA(ah[k], ldB(whT, 128, n0, k * 32, l), ch);
                }
                gi[g] = ci; gh[g] = ch;
            }
            const int col = colb + l16;
            float bi0 = b_ih[col], bi1 = b_ih[HD + col], bi2 = b_ih[2 * HD + col];
            float bh0 = b_hh[col], bh1 = b_hh[HD + col], bh2 = b_hh[2 * HD + col];
            float wac = W_a[HD + col];
            #pragma unroll
            for (int r = 0; r < 4; ++r) {
                const int row = q * 4 + r;
                float rg = sigm(gi[0][r] + bi0 + gh[0][r] + bh0);
                float zg = sigm(gi[1][r] + bi1 + gh[1][r] + bh1);
                float ng = tanh_fast(gi[2][r] + bi2 + rg * (gh[2][r] + bh2));
                float hv = (1.f - zg) * ng + zg * (float)hl[row * 136 + col];
                out[QN + (size_t)(a0 + row) * HD + col] = hv;   // output: h_new
                bufA[row][col] = (half_t)hv;                    // hn (over agg)
                pa[r] = fmaf(hv, wac, pa[r]);
            }
        }
        #pragma unroll
        for (int r = 0; r < 4; ++r) {
            #pragma unroll
            for (int m = 1; m <= 8; m <<= 1) pa[r] += __shfl_xor(pa[r], m);
            if (l16 == 0) atomicAdd(&hnwa[q * 4 + r], pa[r]);
        }
    }
    __syncthreads();   // b3: hn + hnwa complete

    // ---- S4h: che = h_new @ We1h + b_e1 -> xb (over x) ----
    {
        const half_t* we1hT = ws + O_WE1H;
        half8 an[4];
        #pragma unroll
        for (int k = 0; k < 4; ++k) an[k] = *(const half8*)&bufA[l16][k * 32 + q * 8];
        #pragma unroll
        for (int s = 0; s < 2; ++s) {
            const int n0 = (w * 2 + s) * 16;
            f32x4 c = {0.f, 0.f, 0.f, 0.f};
            #pragma unroll
            for (int k = 0; k < 4; ++k) c = MFMA(an[k], ldB(we1hT, 128, n0, k * 32, l), c);
            float bv = b_e1[n0 + l16];
            #pragma unroll
            for (int r = 0; r < 4; ++r)
                xb[(q * 4 + r) * 136 + n0 + l16] = (half_t)(c[r] + bv);
        }
    }
    __syncthreads();   // b4: che complete

    // ---- Phase C: ze = relu([fn|ef]@We1e + che); q-values + agent scalar ----
    {
        const half_t* we1eT = ws + O_WE1E;
        half8 B[4][4];
        float wa0[4], wa1[4];
        #pragma unroll
        for (int nc = 0; nc < 4; ++nc) {
            const int n0 = nc * 32;
            B[nc][0] = ldB(we1eT, 64, n0, 0, l);
            B[nc][1] = ldB(we1eT, 64, n0, 32, l);
            B[nc][2] = ldB(we1eT, 64, n0 + 16, 0, l);
            B[nc][3] = ldB(we1eT, 64, n0 + 16, 32, l);
            wa0[nc] = W_a[n0 + l16];
            wa1[nc] = W_a[n0 + 16 + l16];
        }
        const float ba = b_a[0];

        auto phC = [&](int mt, half8 af0) {
            const int al = w * 4 + mt;
            const int arow = al * 16 + l16;
            half8 af1 = hz;
            if (q == 0) af1 = *(const half8*)&efh[arow][0];
            float qa[4][4];
            #pragma unroll
            for (int r = 0; r < 4; ++r)
                #pragma unroll
                for (int p = 0; p < 4; ++p) qa[r][p] = 0.f;
            float wa_part = 0.f;
            #pragma unroll
            for (int nc = 0; nc < 4; ++nc) {
                const int n0 = nc * 32;
                f32x4 c0 = {0.f, 0.f, 0.f, 0.f}, c1 = {0.f, 0.f, 0.f, 0.f};
                c0 = MFMA(af0, B[nc][0], c0);
                c0 = MFMA(af1, B[nc][1], c0);
                c1 = MFMA(af0, B[nc][2], c1);
                c1 = MFMA(af1, B[nc][3], c1);
                const int col0 = n0 + l16, col1 = n0 + 16 + l16;
                float ch0 = (float)xb[al * 136 + col0], ch1 = (float)xb[al * 136 + col1];
                f32x4 w20 = *(const f32x4*)(W_e2 + col0 * 4);
                f32x4 w21 = *(const f32x4*)(W_e2 + col1 * 4);
                float s0 = 0.f, s1 = 0.f;
                #pragma unroll
                for (int r = 0; r < 4; ++r) {
                    float z0 = fmaxf(c0[r] + ch0, 0.f);
                    float z1 = fmaxf(c1[r] + ch1, 0.f);
                    s0 += z0; s1 += z1;
                    qa[r][0] = fmaf(z0, w20[0], fmaf(z1, w21[0], qa[r][0]));
                    qa[r][1] = fmaf(z0, w20[1], fmaf(z1, w21[1], qa[r][1]));
                    qa[r][2] = fmaf(z0, w20[2], fmaf(z1, w21[2], qa[r][2]));
                    qa[r][3] = fmaf(z0, w20[3], fmaf(z1, w21[3], qa[r][3]));
                }
                s0 += __shfl_xor(s0, 16); s0 += __shfl_xor(s0, 32);
                s1 += __shfl_xor(s1, 16); s1 += __shfl_xor(s1, 32);
                wa_part = fmaf(s0, wa0[nc], fmaf(s1, wa1[nc], wa_part));
            }
            #pragma unroll
            for (int m = 1; m <= 8; m <<= 1)
                #pragma unroll
                for (int r = 0; r < 4; ++r)
                    #pragma unroll
                    for (int p = 0; p < 4; ++p) qa[r][p] += __shfl_xor(qa[r][p], m);
            if (l16 < 4) {
                const int p = l16;
                const float bz = b_e2[p];
                #pragma unroll
                for (int r = 0; r < 4; ++r)
                    out[(size_t)(a0 + al) * QCOLS + (q * 4 + r) * 4 + p] = qa[r][p] + bz;
            }
            #pragma unroll
            for (int m = 1; m <= 8; m <<= 1) wa_part += __shfl_xor(wa_part, m);
            if (l == 0)
                out[(size_t)(a0 + al) * QCOLS + 64] = wa_part + hnwa[al] + ba;
        };
        phC(0, af0k[0]);
        phC(1, af0k[1]);
        phC(2, af0k[2]);
        phC(3, af0k[3]);
    }
}

extern "C" void kernel_launch(void* const* d_in, const int* in_sizes, int n_in,
                              void* d_out, int out_size, void* d_ws, size_t ws_size,
                              hipStream_t stream) {
    const float* feat_nbr   = (const float*)d_in[0];
    const float* feat_agent = (const float*)d_in[1];
    const float* edge_feat  = (const float*)d_in[2];
    const float* h_in       = (const float*)d_in[3];
    const float* W_msg = (const float*)d_in[4];
    const float* b_msg = (const float*)d_in[5];
    const float* W_upd = (const float*)d_in[6];
    const float* b_upd = (const float*)d_in[7];
    const float* W_x   = (const float*)d_in[8];
    const float* W_h   = (const float*)d_in[9];
    const float* b_ih  = (const float*)d_in[10];
    const float* b_hh  = (const float*)d_in[11];
    const float* W_e1  = (const float*)d_in[12];
    const float* b_e1  = (const float*)d_in[13];
    const float* W_e2  = (const float*)d_in[14];
    const float* b_e2  = (const float*)d_in[15];
    const float* W_a   = (const float*)d_in[16];
    const float* b_a   = (const float*)d_in[17];
    const int* src_idx = (const int*)d_in[18];
    // d_in[19] = dst_idx unused: edges grouped by dst, fixed degree 16.
    half_t* ws = (half_t*)d_ws;
    float* out = (float*)d_out;
    const int nblk = NAGENT / AGB;   // 2048

    prep_weights<<<(W_TOTAL + 255) / 256, 256, 0, stream>>>(W_msg, W_upd, W_x, W_h, W_e1, ws);
    k_fused<<<nblk, 256, 0, stream>>>(feat_nbr, feat_agent, edge_feat, h_in,
                                      b_msg, b_upd, b_ih, b_hh, b_e1,
                                      W_e2, b_e2, W_a, b_a, src_idx, ws, out);
}